// Round 4
// baseline (30.066 us; speedup 1.0000x reference)
//
#include <hip/hip_runtime.h>
#include <math.h>

#define DIM_   128
#define NAT_   16
#define NTOT_  1024
#define BMOL_  64
#define OFFB_  1008.0f
#define EPSF_  1e-12f

__device__ __forceinline__ float4 ld4(const float* p) {
    return *reinterpret_cast<const float4*>(p);
}
__device__ __forceinline__ void st4(float* p, float4 v) {
    *reinterpret_cast<float4*>(p) = v;
}

// Single fused kernel: 64 blocks (1/molecule) x 512 threads.
// Phase 1 (atom-major: thread = (atom j, 4 dims c0..c0+3)):
//   embed -> contri -> message -> L2norm -> bond gather (nsq + t_j in one pass)
//   -> per-molecule columns TnIn, Sb, Mb.
// Software grid barrier on Sb, then phase 2 (slot-major): S -> tn -> MLP -> out.
__global__ __launch_bounds__(512) void fused(
    const int* __restrict__ fp, const float* __restrict__ Efp,
    const float* __restrict__ Wfp, const float* __restrict__ bfp,
    const float* __restrict__ adj, const int* __restrict__ bidx,
    const float* __restrict__ Ebond,
    const float* __restrict__ W0, const float* __restrict__ b0,
    const float* __restrict__ W1, const float* __restrict__ b1,
    const float* __restrict__ Wp, const float* __restrict__ bp,
    float* __restrict__ Sb_g, unsigned* __restrict__ bar,
    float* __restrict__ out)
{
    const int m = blockIdx.x, base = m * NAT_;
    const int t = threadIdx.x;

    __shared__ __align__(16) float mpsS[NAT_][DIM_];   // embeddings, then mpsn
    __shared__ __align__(16) float conS[NAT_][DIM_];   // contri, then p = msc*t_j
    __shared__ __align__(16) float mscS[NAT_][DIM_];
    __shared__ __align__(16) float adjS[NAT_][NAT_];
    __shared__ __align__(16) int   bSh[NAT_][NAT_];
    __shared__ float tnS[DIM_];   // TnIn, then x0
    __shared__ float vS[DIM_];    // tn (layer-1 input)
    __shared__ float xS[4][DIM_]; // slot partials
    __shared__ float sbS[DIM_];
    __shared__ float mbS[DIM_];
    __shared__ float r2[2];

    const int j  = t >> 5;        // atom 0..15
    const int q  = t & 31;
    const int c0 = q * 4;

    // ---- loads: embeddings (1 float4/thread), adj + bond blocks ----
    const float4 emb = ld4(&Efp[(size_t)fp[base + j] * DIM_ + c0]);
    st4(&mpsS[j][c0], emb);
    if (t < 64) {
        const int jj = t >> 2, qq = (t & 3) * 4;
        st4(&adjS[jj][qq], ld4(&adj[(size_t)(base + jj) * NTOT_ + base + qq]));
    } else if (t < 128) {
        const int tt = t - 64, jj = tt >> 2, qq = (tt & 3) * 4;
        *reinterpret_cast<int4*>(&bSh[jj][qq]) =
            *reinterpret_cast<const int4*>(&bidx[(size_t)(base + jj) * NTOT_ + base + qq]);
    }
    __syncthreads();

    // ---- contri[j][c0..3] = relu(mps[j] @ Wfp + b) ----
    float4 acc = ld4(&bfp[c0]);
    #pragma unroll 8
    for (int k = 0; k < DIM_; k += 4) {
        const float4 mk = ld4(&mpsS[j][k]);
        const float4 w0 = ld4(&Wfp[(size_t)(k + 0) * DIM_ + c0]);
        const float4 w1 = ld4(&Wfp[(size_t)(k + 1) * DIM_ + c0]);
        const float4 w2 = ld4(&Wfp[(size_t)(k + 2) * DIM_ + c0]);
        const float4 w3 = ld4(&Wfp[(size_t)(k + 3) * DIM_ + c0]);
        acc.x += mk.x * w0.x + mk.y * w1.x + mk.z * w2.x + mk.w * w3.x;
        acc.y += mk.x * w0.y + mk.y * w1.y + mk.z * w2.y + mk.w * w3.y;
        acc.z += mk.x * w0.z + mk.y * w1.z + mk.z * w2.z + mk.w * w3.z;
        acc.w += mk.x * w0.w + mk.y * w1.w + mk.z * w2.w + mk.w * w3.w;
    }
    float4 con;
    con.x = fmaxf(acc.x, 0.f); con.y = fmaxf(acc.y, 0.f);
    con.z = fmaxf(acc.z, 0.f); con.w = fmaxf(acc.w, 0.f);
    st4(&conS[j][c0], con);
    __syncthreads();

    // ---- message + row L2 norm (half-wave shuffle reduce) ----
    float4 ms = emb;
    #pragma unroll
    for (int i = 0; i < NAT_; ++i) {
        const float a = adjS[j][i];
        const float4 cv = ld4(&conS[i][c0]);
        ms.x += a * cv.x; ms.y += a * cv.y; ms.z += a * cv.z; ms.w += a * cv.w;
    }
    float v = ms.x * ms.x + ms.y * ms.y + ms.z * ms.z + ms.w * ms.w;
    #pragma unroll
    for (int o = 16; o > 0; o >>= 1) v += __shfl_xor(v, o, 64);
    const float nrm = fmaxf(sqrtf(v), EPSF_);
    float4 mn;
    mn.x = ms.x / nrm; mn.y = ms.y / nrm; mn.z = ms.z / nrm; mn.w = ms.w / nrm;
    st4(&mpsS[j][c0], mn);              // own row only; no cross-group hazard
    __syncthreads();

    // ---- bond gather: nsq + t_j in one pass over 16 in-block bonds ----
    const float4 e0 = ld4(&Ebond[c0]);
    float4 nsq;
    nsq.x = OFFB_ * e0.x * e0.x; nsq.y = OFFB_ * e0.y * e0.y;
    nsq.z = OFFB_ * e0.z * e0.z; nsq.w = OFFB_ * e0.w * e0.w;
    float4 tj = {0.f, 0.f, 0.f, 0.f};
    int bid[NAT_];
    #pragma unroll
    for (int i = 0; i < NAT_; ++i) bid[i] = bSh[j][i];
    #pragma unroll
    for (int i = 0; i < NAT_; ++i) {
        const float4 ev = ld4(&Ebond[(size_t)bid[i] * DIM_ + c0]);
        const float4 mi = ld4(&mpsS[i][c0]);
        nsq.x += ev.x * ev.x; nsq.y += ev.y * ev.y;
        nsq.z += ev.z * ev.z; nsq.w += ev.w * ev.w;
        tj.x += ev.x * mi.x; tj.y += ev.y * mi.y;
        tj.z += ev.z * mi.z; tj.w += ev.w * mi.w;
    }
    float4 msc;
    msc.x = mn.x / fmaxf(sqrtf(nsq.x), EPSF_);
    msc.y = mn.y / fmaxf(sqrtf(nsq.y), EPSF_);
    msc.z = mn.z / fmaxf(sqrtf(nsq.z), EPSF_);
    msc.w = mn.w / fmaxf(sqrtf(nsq.w), EPSF_);
    st4(&mscS[j][c0], msc);
    float4 p;
    p.x = msc.x * tj.x; p.y = msc.y * tj.y; p.z = msc.z * tj.z; p.w = msc.w * tj.w;
    st4(&conS[j][c0], p);               // reuse conS for p (contri already consumed)
    __syncthreads();

    // ---- column reductions over atoms (3 warps) ----
    if (t < 96) {
        const int cc = (t & 31) * 4;
        float4 a = {0.f, 0.f, 0.f, 0.f};
        if (t < 32) {
            #pragma unroll
            for (int i = 0; i < NAT_; ++i) {
                const float4 u = ld4(&conS[i][cc]);
                a.x += u.x; a.y += u.y; a.z += u.z; a.w += u.w;
            }
            st4(&tnS[cc], a);                              // TnIn
        } else if (t < 64) {
            #pragma unroll
            for (int i = 0; i < NAT_; ++i) {
                const float4 u = ld4(&mscS[i][cc]);
                a.x += u.x; a.y += u.y; a.z += u.z; a.w += u.w;
            }
            st4(&sbS[cc], a);
            // publish Sb at agent scope (coherent across XCDs)
            __hip_atomic_store(&Sb_g[(size_t)m * DIM_ + cc + 0], a.x, __ATOMIC_RELAXED, __HIP_MEMORY_SCOPE_AGENT);
            __hip_atomic_store(&Sb_g[(size_t)m * DIM_ + cc + 1], a.y, __ATOMIC_RELAXED, __HIP_MEMORY_SCOPE_AGENT);
            __hip_atomic_store(&Sb_g[(size_t)m * DIM_ + cc + 2], a.z, __ATOMIC_RELAXED, __HIP_MEMORY_SCOPE_AGENT);
            __hip_atomic_store(&Sb_g[(size_t)m * DIM_ + cc + 3], a.w, __ATOMIC_RELAXED, __HIP_MEMORY_SCOPE_AGENT);
        } else {
            #pragma unroll
            for (int i = 0; i < NAT_; ++i) {
                const float4 u = ld4(&mpsS[i][cc]);        // mpsn
                a.x += u.x; a.y += u.y; a.z += u.z; a.w += u.w;
            }
            st4(&mbS[cc], a);
        }
    }
    __syncthreads();

    // ---- software grid barrier ----
    if (t == 0) {
        __threadfence();
        __hip_atomic_fetch_add(bar, 1u, __ATOMIC_ACQ_REL, __HIP_MEMORY_SCOPE_AGENT);
        unsigned cur;
        do {
            __builtin_amdgcn_s_sleep(2);
            cur = __hip_atomic_load(bar, __ATOMIC_ACQUIRE, __HIP_MEMORY_SCOPE_AGENT);
        } while (cur < (unsigned)BMOL_);
    }
    __syncthreads();

    // ---- phase 2: slot-major (c = t&127, s2 = t>>7) ----
    const int c  = t & 127;
    const int s2 = t >> 7;
    float S = 0.0f;
    #pragma unroll
    for (int r = 0; r < 16; ++r) {
        const int mm = s2 * 16 + r;
        S += __hip_atomic_load(&Sb_g[(size_t)mm * DIM_ + c], __ATOMIC_RELAXED, __HIP_MEMORY_SCOPE_AGENT);
    }
    xS[s2][c] = S;
    __syncthreads();
    if (s2 == 0) {
        const float Sall = xS[0][c] + xS[1][c] + xS[2][c] + xS[3][c];
        vS[c] = tnS[c] + Ebond[c] * (Sall - sbS[c]) * mbS[c];   // tn
    }
    __syncthreads();

    // layer 1: x0 = relu(tn @ W0 + b0), d-loop split over 4 slots
    float a1 = 0.0f;
    #pragma unroll 8
    for (int r = 0; r < 32; ++r) {
        const int d = s2 * 32 + r;
        a1 += vS[d] * W0[(size_t)d * DIM_ + c];
    }
    xS[s2][c] = a1;
    __syncthreads();
    if (s2 == 0) tnS[c] = fmaxf(xS[0][c] + xS[1][c] + xS[2][c] + xS[3][c] + b0[c], 0.0f);
    __syncthreads();

    // layer 2
    float a2 = 0.0f;
    #pragma unroll 8
    for (int r = 0; r < 32; ++r) {
        const int d = s2 * 32 + r;
        a2 += tnS[d] * W1[(size_t)d * DIM_ + c];
    }
    xS[s2][c] = a2;
    __syncthreads();
    if (s2 == 0) {
        const float x1 = fmaxf(xS[0][c] + xS[1][c] + xS[2][c] + xS[3][c] + b1[c], 0.0f);
        float vv = x1 * Wp[c];
        #pragma unroll
        for (int o = 32; o > 0; o >>= 1) vv += __shfl_xor(vv, o, 64);
        if ((c & 63) == 0) r2[c >> 6] = vv;
    }
    __syncthreads();
    if (t == 0) out[m] = r2[0] + r2[1] + bp[0];
}

extern "C" void kernel_launch(void* const* d_in, const int* in_sizes, int n_in,
                              void* d_out, int out_size, void* d_ws, size_t ws_size,
                              hipStream_t stream) {
    const int*   fingerprints = (const int*)  d_in[0];
    const float* adjacency    = (const float*)d_in[1];
    const int*   bond_index   = (const int*)  d_in[2];
    const float* E_fp         = (const float*)d_in[3];
    const float* E_bond       = (const float*)d_in[4];
    const float* W_fp         = (const float*)d_in[5];
    const float* b_fp         = (const float*)d_in[6];
    const float* W_out0       = (const float*)d_in[7];
    const float* b_out0       = (const float*)d_in[8];
    const float* W_out1       = (const float*)d_in[9];
    const float* b_out1       = (const float*)d_in[10];
    const float* W_prop       = (const float*)d_in[11];
    const float* b_prop       = (const float*)d_in[12];
    float* out = (float*)d_out;

    float* Sb = (float*)d_ws;                                       // [64,128]
    unsigned* bar = (unsigned*)((char*)d_ws + (size_t)BMOL_ * DIM_ * sizeof(float));

    hipMemsetAsync(bar, 0, sizeof(unsigned), stream);
    fused<<<BMOL_, 512, 0, stream>>>(fingerprints, E_fp, W_fp, b_fp,
                                     adjacency, bond_index, E_bond,
                                     W_out0, b_out0, W_out1, b_out1, W_prop, b_prop,
                                     Sb, bar, out);
}

// Round 5
// 23.479 us; speedup vs baseline: 1.2806x; 1.2806x over previous
//
#include <hip/hip_runtime.h>
#include <math.h>

#define DIM_   128
#define NAT_   16
#define NTOT_  1024
#define BMOL_  64
#define OFFB_  1008.0f
#define EPSF_  1e-12f

// Kernel A: per-molecule, 1024 threads (16 waves). Thread t: c = t&127 (dim),
// s = t>>7 (slot 0..7) owning atoms j0=2s, j1=2s+1.
// embed -> contri -> message -> L2norm -> batched bond gather (32 outstanding
// scalar loads/thread) -> TnIn, Mb, Sb.
__global__ __launch_bounds__(1024) void kA(const int* __restrict__ fp,
                                           const float* __restrict__ Efp,
                                           const float* __restrict__ Wfp,
                                           const float* __restrict__ bfp,
                                           const float* __restrict__ adj,
                                           const int* __restrict__ bidx,
                                           const float* __restrict__ Ebond,
                                           float* __restrict__ TnIn_g,
                                           float* __restrict__ Mb_g,
                                           float* __restrict__ Sb_g) {
    const int m = blockIdx.x, base = m * NAT_;
    const int t = threadIdx.x;
    const int c = t & 127;
    const int s = t >> 7;
    const int j0 = 2 * s, j1 = 2 * s + 1;

    __shared__ float mpsS[NAT_][DIM_];     // embeddings, later mpsn
    __shared__ float conS[NAT_][DIM_];
    __shared__ float adjS[NAT_][NAT_];
    __shared__ int   bSh[NAT_][NAT_];
    __shared__ float redS[NAT_][2];
    __shared__ float nrmS[NAT_];
    __shared__ float red4[4][NAT_][DIM_];  // 32 KB: inblock partials, 2-stage
    __shared__ float sb8[8][DIM_];
    __shared__ float tnp8[8][DIM_];

    // embeddings: 2048 elems / 1024 threads = 2 each (rows 0-7, then 8-15)
    {
        int j = t >> 7, cc = t & 127;
        mpsS[j][cc] = Efp[(size_t)fp[base + j] * DIM_ + cc];
        j += 8;
        mpsS[j][cc] = Efp[(size_t)fp[base + j] * DIM_ + cc];
    }
    if (t < 256) {
        const int j = t >> 4, i = t & 15;
        adjS[j][i] = adj[(size_t)(base + j) * NTOT_ + base + i];
    } else if (t < 512) {
        const int tt = t - 256, j = tt >> 4, i = tt & 15;
        bSh[j][i] = bidx[(size_t)(base + j) * NTOT_ + base + i];
    }
    __syncthreads();

    // contri for my 2 atoms
    float a0 = bfp[c];
    float a1 = a0;
    #pragma unroll 8
    for (int k = 0; k < DIM_; ++k) {
        const float w = Wfp[(size_t)k * DIM_ + c];
        a0 += mpsS[j0][k] * w;
        a1 += mpsS[j1][k] * w;
    }
    conS[j0][c] = fmaxf(a0, 0.0f);
    conS[j1][c] = fmaxf(a1, 0.0f);
    __syncthreads();

    // message + row L2 norm
    float ms0 = mpsS[j0][c], ms1 = mpsS[j1][c];
    #pragma unroll
    for (int i = 0; i < NAT_; ++i) {
        const float cv = conS[i][c];
        ms0 += adjS[j0][i] * cv;
        ms1 += adjS[j1][i] * cv;
    }
    float v0 = ms0 * ms0, v1 = ms1 * ms1;
    #pragma unroll
    for (int o = 32; o > 0; o >>= 1) {
        v0 += __shfl_xor(v0, o, 64);
        v1 += __shfl_xor(v1, o, 64);
    }
    const int half = (t >> 6) & 1;
    if ((t & 63) == 0) { redS[j0][half] = v0; redS[j1][half] = v1; }
    __syncthreads();
    if (t < NAT_) nrmS[t] = fmaxf(sqrtf(redS[t][0] + redS[t][1]), EPSF_);
    __syncthreads();

    const float mn0 = ms0 / nrmS[j0];
    const float mn1 = ms1 / nrmS[j1];
    mpsS[j0][c] = mn0;                     // own rows only; read after next sync
    mpsS[j1][c] = mn1;

    // ---- batched bond gather: 32 independent loads in flight ----
    const float e0 = Ebond[c];
    const float e0sq = OFFB_ * e0 * e0;
    float evA[NAT_], evB[NAT_];
    #pragma unroll
    for (int i = 0; i < NAT_; ++i)
        evA[i] = Ebond[(size_t)bSh[j0][i] * DIM_ + c];
    #pragma unroll
    for (int i = 0; i < NAT_; ++i)
        evB[i] = Ebond[(size_t)bSh[j1][i] * DIM_ + c];
    float nsqA = e0sq, nsqB = e0sq;
    #pragma unroll
    for (int i = 0; i < NAT_; ++i) {
        nsqA += evA[i] * evA[i];
        nsqB += evB[i] * evB[i];
    }
    const float mscA = mn0 / fmaxf(sqrtf(nsqA), EPSF_);
    const float mscB = mn1 / fmaxf(sqrtf(nsqB), EPSF_);
    float accIn[NAT_];
    #pragma unroll
    for (int i = 0; i < NAT_; ++i)
        accIn[i] = mscA * evA[i] + mscB * evB[i];

    // ---- 2-stage slot reduction (keeps LDS under 64 KB) ----
    if (s < 4) {
        #pragma unroll
        for (int i = 0; i < NAT_; ++i) red4[s][i][c] = accIn[i];
    }
    sb8[s][c] = mscA + mscB;
    __syncthreads();
    if (s >= 4) {
        #pragma unroll
        for (int i = 0; i < NAT_; ++i) red4[s - 4][i][c] += accIn[i];
    }
    __syncthreads();

    // in_i for own atoms -> TnIn partial
    float in0 = 0.0f, in1 = 0.0f;
    #pragma unroll
    for (int s2 = 0; s2 < 4; ++s2) {
        in0 += red4[s2][j0][c];
        in1 += red4[s2][j1][c];
    }
    tnp8[s][c] = in0 * mn0 + in1 * mn1;
    __syncthreads();

    if (s == 0) {
        float TnIn = 0.0f, Sb = 0.0f, Mb = 0.0f;
        #pragma unroll
        for (int s2 = 0; s2 < 8; ++s2) {
            TnIn += tnp8[s2][c];
            Sb   += sb8[s2][c];
        }
        #pragma unroll
        for (int j = 0; j < NAT_; ++j) Mb += mpsS[j][c];
        TnIn_g[m * DIM_ + c] = TnIn;
        Sb_g[m * DIM_ + c]   = Sb;
        Mb_g[m * DIM_ + c]   = Mb;
    }
}

// Kernel B: per-molecule, 128 threads. S -> tn -> MLP -> out. No gathers.
__global__ __launch_bounds__(128) void kB(const float* __restrict__ Ebond,
                                          const float* __restrict__ TnIn_g,
                                          const float* __restrict__ Mb_g,
                                          const float* __restrict__ Sb_g,
                                          const float* __restrict__ W0, const float* __restrict__ b0,
                                          const float* __restrict__ W1, const float* __restrict__ b1,
                                          const float* __restrict__ Wp, const float* __restrict__ bp,
                                          float* __restrict__ out) {
    const int m = blockIdx.x, c = threadIdx.x;
    __shared__ float tnS[DIM_];
    __shared__ float r2[2];

    float S = 0.0f;
    #pragma unroll 8
    for (int mm = 0; mm < BMOL_; ++mm) S += Sb_g[mm * DIM_ + c];
    const float tn = TnIn_g[m * DIM_ + c]
                   + Ebond[c] * (S - Sb_g[m * DIM_ + c]) * Mb_g[m * DIM_ + c];
    tnS[c] = tn;
    __syncthreads();

    float x0 = b0[c];
    #pragma unroll 8
    for (int d = 0; d < DIM_; ++d) x0 += tnS[d] * W0[(size_t)d * DIM_ + c];
    x0 = fmaxf(x0, 0.0f);
    __syncthreads();
    tnS[c] = x0;
    __syncthreads();
    float x1 = b1[c];
    #pragma unroll 8
    for (int d = 0; d < DIM_; ++d) x1 += tnS[d] * W1[(size_t)d * DIM_ + c];
    x1 = fmaxf(x1, 0.0f);

    float v = x1 * Wp[c];
    #pragma unroll
    for (int o = 32; o > 0; o >>= 1) v += __shfl_xor(v, o, 64);
    if ((c & 63) == 0) r2[c >> 6] = v;
    __syncthreads();
    if (c == 0) out[m] = r2[0] + r2[1] + bp[0];
}

extern "C" void kernel_launch(void* const* d_in, const int* in_sizes, int n_in,
                              void* d_out, int out_size, void* d_ws, size_t ws_size,
                              hipStream_t stream) {
    const int*   fingerprints = (const int*)  d_in[0];
    const float* adjacency    = (const float*)d_in[1];
    const int*   bond_index   = (const int*)  d_in[2];
    const float* E_fp         = (const float*)d_in[3];
    const float* E_bond       = (const float*)d_in[4];
    const float* W_fp         = (const float*)d_in[5];
    const float* b_fp         = (const float*)d_in[6];
    const float* W_out0       = (const float*)d_in[7];
    const float* b_out0       = (const float*)d_in[8];
    const float* W_out1       = (const float*)d_in[9];
    const float* b_out1       = (const float*)d_in[10];
    const float* W_prop       = (const float*)d_in[11];
    const float* b_prop       = (const float*)d_in[12];
    float* out = (float*)d_out;

    float* ws = (float*)d_ws;
    const size_t MD = (size_t)BMOL_ * DIM_;
    float* TnIn = ws;           // [64,128]
    float* Mb   = ws + MD;      // [64,128]
    float* Sb   = ws + 2 * MD;  // [64,128]

    kA<<<BMOL_, 1024, 0, stream>>>(fingerprints, E_fp, W_fp, b_fp, adjacency, bond_index,
                                   E_bond, TnIn, Mb, Sb);
    kB<<<BMOL_, DIM_, 0, stream>>>(E_bond, TnIn, Mb, Sb,
                                   W_out0, b_out0, W_out1, b_out1, W_prop, b_prop, out);
}